// Round 8
// baseline (381.442 us; speedup 1.0000x reference)
//
#include <hip/hip_runtime.h>
#include <math.h>

#define DIM 1024
#define ROWS 16384
#define SEQ 4096
#define MARGIN 0.012f
#define MAXC 24

typedef __bf16 v8bf __attribute__((ext_vector_type(8)));
typedef float v4f __attribute__((ext_vector_type(4)));
typedef int v8i __attribute__((ext_vector_type(8)));

__device__ __forceinline__ unsigned short f2bf(float f){
  unsigned u = __float_as_uint(f);
  u = u + 0x7FFFu + ((u >> 16) & 1u);   // RNE
  return (unsigned short)(u >> 16);
}
__device__ __forceinline__ float bf2f(unsigned short h){
  return __uint_as_float(((unsigned)h) << 16);
}
__device__ __forceinline__ unsigned short relu_bf(unsigned short h){
  return (h & 0x8000u) ? (unsigned short)0 : h;
}
// SW float -> OCP e4m3fn (RNE, saturating)
__device__ __forceinline__ unsigned f2fp8(float f){
  float a = fabsf(f);
  unsigned sign = (__float_as_uint(f) >> 24) & 0x80u;
  if (a >= 448.f) return sign | 0x7Eu;
  if (a < 0.015625f){                       // subnormal, step 2^-9
    int k = (int)rintf(a * 512.f);          // RNE
    if (k >= 8) return sign | 0x08u;
    return sign | (unsigned)k;
  }
  unsigned u = __float_as_uint(a);
  u += 0x7FFFFu + ((u >> 20) & 1u);         // RNE at 3 mantissa bits
  int e = (int)((u >> 23) & 0xFFu) - 127;
  unsigned m = (u >> 20) & 7u;
  if (e > 8) return sign | 0x7Eu;
  return sign | ((unsigned)(e + 7) << 3) | m;
}
__device__ __forceinline__ void lds_fence(){
  __asm__ volatile("s_waitcnt lgkmcnt(0)" ::: "memory");
}

// ---- fused convert: y<16 x->bf16; y=16,17 gate/mag W->bf16; y=18..20 q/k/p W->fp8(x32) ----
__global__ __launch_bounds__(256) void cvt_all(
    const float* __restrict__ x,
    const float* __restrict__ w0, const float* __restrict__ w1,
    const float* __restrict__ w2, const float* __restrict__ w3,
    const float* __restrict__ w4,
    unsigned short* __restrict__ xbf, unsigned short* __restrict__ wbf,
    unsigned char* __restrict__ wf8){
  const int y = blockIdx.y;
  int i = (blockIdx.x * 256 + threadIdx.x) * 4;
  if (y < 16){
    const float* s = x + ((size_t)y << 20);
    float4 f = *(const float4*)(s + i);
    ushort4 o; o.x = f2bf(f.x); o.y = f2bf(f.y); o.z = f2bf(f.z); o.w = f2bf(f.w);
    *(ushort4*)(xbf + ((size_t)y << 20) + i) = o;
  } else if (y < 18){
    const float* s = (y == 16) ? w0 : w1;
    float4 f = *(const float4*)(s + i);
    ushort4 o; o.x = f2bf(f.x); o.y = f2bf(f.y); o.z = f2bf(f.z); o.w = f2bf(f.w);
    *(ushort4*)(wbf + ((size_t)(y - 16) << 20) + i) = o;
  } else {
    const float* s = (y == 18) ? w2 : ((y == 19) ? w3 : w4);
    float4 f = *(const float4*)(s + i);
    unsigned u = f2fp8(f.x * 32.f) | (f2fp8(f.y * 32.f) << 8) |
                 (f2fp8(f.z * 32.f) << 16) | (f2fp8(f.w * 32.f) << 24);
    *(unsigned*)(wf8 + ((size_t)(y - 18) << 20) + i) = u;
  }
}

#define GBAR() asm volatile("s_barrier" ::: "memory")
#define GLGKM0() { asm volatile("s_waitcnt lgkmcnt(0)" ::: "memory"); __builtin_amdgcn_sched_barrier(0); }
#define GVM8() asm volatile("s_waitcnt vmcnt(8)" ::: "memory")

#define GLD1(srcp, dsto) __builtin_amdgcn_global_load_lds( \
    (const __attribute__((address_space(1))) void*)(srcp), \
    (__attribute__((address_space(3))) void*)(lds + (dsto)), 16, 0, 0)

// =====================================================================
// GEMM1 (bf16), R8: 128x128 tile, 4 waves, 64KB dbuf LDS -> 2 blocks/CU.
// Clone of the R7-verified gemm8 structure (identical byte geometry:
// 128 rows x 128B, XOR swizzle byte^=((row&7)<<4), 8 GLDs/stage,
// counted vmcnt(8), one barrier pair per K-tile). Rationale: the 512-thr
// 256^2 version (78us, MfmaUtil 36%) had acc[8][4]=128 regs + 128KB LDS
// -> 1 lockstep block/CU; every barrier stalled the whole CU. Two
// independent 4-wave blocks overlap read/barrier phases with MFMA.
// Per-output K order unchanged (X asc, k-half 0 then 1) -> bit-identical.
// =====================================================================
__global__ __launch_bounds__(256, 2) void gemm_bt(
    const unsigned short* __restrict__ A, const unsigned short* __restrict__ B,
    const float* __restrict__ bias0, const float* __restrict__ bias1,
    unsigned short* __restrict__ C0, unsigned short* __restrict__ C1)
{
  extern __shared__ unsigned char lds[];
  const int t = threadIdx.x;
  const int lane = t & 63, wave = t >> 6;
  const int wm = (wave >> 1) * 64;                  // 2(M) x 2(N) wave grid
  const int wn = (wave & 1) * 64;
  const int ar = lane & 15, aq = lane >> 4;

  const int bid = blockIdx.x;                       // 2048 blocks
  const int loc = bid >> 3;                         // 256 per XCD
  const int m0 = ((bid & 7) * 16 + (loc & 15)) * 128;   // m-fast within XCD
  const int n0 = (loc >> 4) * 128;                  // n-tile in [0,16)

  const unsigned char* Ab = (const unsigned char*)A + (size_t)m0 * 2048;
  const unsigned char* Bb = (const unsigned char*)B + (size_t)n0 * 2048;

  // staging: 4 chunks/thread per operand, inverse-swizzled global source
  int offb[4];
#pragma unroll
  for (int i = 0; i < 4; i++){
    int d = i * 4096 + t * 16;
    int row = d >> 7;
    offb[i] = row * 2048 + ((d & 127) ^ ((row & 7) << 4));
  }
  auto stage = [&](int kt, int p){                  // 8 GLDs/thread
#pragma unroll
    for (int i = 0; i < 4; i++)
      GLD1(Ab + offb[i] + kt * 128, p * 32768 + i * 4096 + t * 16);
#pragma unroll
    for (int i = 0; i < 4; i++)
      GLD1(Bb + offb[i] + kt * 128, p * 32768 + 16384 + i * 4096 + t * 16);
  };
  // fragment read: tile row r, k-half h (32 bf16 = 64B), 16B slot aq
  auto rdf = [&](int boff, int r, int h) -> v8bf {
    int base = boff + r * 128 + ((h * 64 + aq * 16) ^ ((r & 7) << 4));
    return *(const v8bf*)(lds + base);
  };

  v4f acc[4][4];
#pragma unroll
  for (int i = 0; i < 4; i++)
#pragma unroll
    for (int j = 0; j < 4; j++) acc[i][j] = v4f{0.f, 0.f, 0.f, 0.f};

  // prologue: tile0 -> buf0, tile1 -> buf1 (16 GLDs/thread)
  stage(0, 0); stage(1, 1);
  GVM8();                        // tile0 landed; tile1 in flight
  GBAR();

  for (int X = 0; X < 16; X++){
    const int p = X & 1, pb = p * 32768;
    v8bf af0[4], af1[4], bf0[4], bf1[4];
#pragma unroll
    for (int mi = 0; mi < 4; mi++){
      af0[mi] = rdf(pb, wm + mi * 16 + ar, 0);
      af1[mi] = rdf(pb, wm + mi * 16 + ar, 1);
    }
#pragma unroll
    for (int ni = 0; ni < 4; ni++){
      bf0[ni] = rdf(pb + 16384, wn + ni * 16 + ar, 0);
      bf1[ni] = rdf(pb + 16384, wn + ni * 16 + ar, 1);
    }
    GLGKM0();                    // frags in regs
    GBAR();                      // ALL waves done reading buf p
    const int kt2 = (X + 2 < 16) ? X + 2 : X;  // tail: benign same-data re-stage
    stage(kt2, p);               // overwrite buf p with tile X+2
    __builtin_amdgcn_s_setprio(1);
#pragma unroll
    for (int mi = 0; mi < 4; mi++)
#pragma unroll
      for (int ni = 0; ni < 4; ni++)
        acc[mi][ni] = __builtin_amdgcn_mfma_f32_16x16x32_bf16(af0[mi], bf0[ni], acc[mi][ni], 0, 0, 0);
#pragma unroll
    for (int mi = 0; mi < 4; mi++)
#pragma unroll
      for (int ni = 0; ni < 4; ni++)
        acc[mi][ni] = __builtin_amdgcn_mfma_f32_16x16x32_bf16(af1[mi], bf1[ni], acc[mi][ni], 0, 0, 0);
    __builtin_amdgcn_s_setprio(0);
    GVM8();                      // tile X+1 landed; X+2 stays in flight
    GBAR();
  }

  // ---- epilogue: LDS repack (+bias) -> full-line coalesced stores ----
  asm volatile("s_waitcnt vmcnt(0)" ::: "memory");
  __syncthreads();
  const int os = n0 >> 10;
  unsigned short* Cp = (os == 0) ? C0 : C1;
  const float* bp = (os == 0) ? bias0 : bias1;
  const int colbase = n0 & (DIM - 1);
  unsigned short* lt = (unsigned short*)lds;       // [32][136] bf16 repack tile
  const int lrw = (wave >> 1) * 16 + aq * 4;       // + rr -> LDS row 0..31
  const int colc0 = (wave & 1) * 64;
  float bv[4];
#pragma unroll
  for (int ni = 0; ni < 4; ni++) bv[ni] = bp[colbase + colc0 + ni * 16 + ar];
  const int lrow = t >> 3;                         // 32 rows x 8 thr
  const int cseg = (t & 7) * 16;                   // 16 bf16 = 32B per thread
  const size_t grb = (size_t)(m0 + (lrow >> 4) * 64 + (lrow & 15)) * DIM + colbase + cseg;
#pragma unroll
  for (int mi = 0; mi < 4; mi++){
#pragma unroll
    for (int ni = 0; ni < 4; ni++){
      const int colc = colc0 + ni * 16 + ar;
#pragma unroll
      for (int rr = 0; rr < 4; rr++)
        lt[(lrw + rr) * 136 + colc] = f2bf(acc[mi][ni][rr] + bv[ni]);
    }
    __syncthreads();
    uint4 v0 = *(const uint4*)&lt[lrow * 136 + cseg];
    uint4 v1 = *(const uint4*)&lt[lrow * 136 + cseg + 8];
    *(uint4*)(Cp + grb + (size_t)mi * 16 * DIM) = v0;
    *(uint4*)(Cp + grb + (size_t)mi * 16 * DIM + 8) = v1;
    __syncthreads();
  }
}

// =====================================================================
// GEMM2 (MX-fp8): 128x128 tile, 4 waves, 64KB dbuf LDS, 2 blocks/CU.
// Verified R7. m-fast XCD supertiling; XOR-swizzled staging + pair reads.
// =====================================================================
__global__ __launch_bounds__(256, 2) void gemm8(
    const unsigned char* __restrict__ A, const unsigned char* __restrict__ B,
    unsigned short* __restrict__ C0, unsigned short* __restrict__ C1,
    unsigned short* __restrict__ C2)
{
  extern __shared__ unsigned char lds[];
  const int t = threadIdx.x;
  const int lane = t & 63, wave = t >> 6;
  const int wm = (wave >> 1) * 64;                  // 2(M) x 2(N) wave grid
  const int wn = (wave & 1) * 64;
  const int ar = lane & 15, aq = lane >> 4;

  const int bid = blockIdx.x;                       // 3072 blocks
  const int loc = bid >> 3;                         // 384 per XCD
  const int m0 = ((bid & 7) * 16 + (loc & 15)) * 128;   // m-fast within XCD
  const int n0 = (loc >> 4) * 128;                  // n in [0,24)

  const unsigned char* Ab = A + ((size_t)m0 << 10);
  const unsigned char* Bb = B + ((size_t)n0 << 10);

  // staging: 4 chunks/thread per operand, inverse-swizzled global source
  int offb[4];
#pragma unroll
  for (int i = 0; i < 4; i++){
    int d = i * 4096 + t * 16;
    int row = d >> 7;
    offb[i] = row * 1024 + ((d & 127) ^ ((row & 7) << 4));
  }
  auto stage = [&](int kt, int p){                  // 8 GLDs/thread
#pragma unroll
    for (int i = 0; i < 4; i++)
      GLD1(Ab + offb[i] + kt * 128, p * 32768 + i * 4096 + t * 16);
#pragma unroll
    for (int i = 0; i < 4; i++)
      GLD1(Bb + offb[i] + kt * 128, p * 32768 + 16384 + i * 4096 + t * 16);
  };
  // fragment read: tile row r, K-bytes aq*32..+32, swizzled pair read
  auto rdfrag = [&](int boff, int r) -> v8i {
    int base = boff + r * 128 + ((aq * 32) ^ ((r & 7) << 4));
    int4 lo = *(const int4*)(lds + base);
    int4 hi = *(const int4*)(lds + (base ^ 16));
    v8i v; v[0]=lo.x; v[1]=lo.y; v[2]=lo.z; v[3]=lo.w;
           v[4]=hi.x; v[5]=hi.y; v[6]=hi.z; v[7]=hi.w;
    return v;
  };

  v4f acc[4][4];
#pragma unroll
  for (int i = 0; i < 4; i++)
#pragma unroll
    for (int j = 0; j < 4; j++) acc[i][j] = v4f{0.f, 0.f, 0.f, 0.f};

  // prologue: tile0 -> buf0, tile1 -> buf1 (16 GLDs/thread)
  stage(0, 0); stage(1, 1);
  GVM8();                        // tile0 landed; tile1 in flight
  GBAR();

  for (int X = 0; X < 8; X++){
    const int p = X & 1, pb = p * 32768;
    v8i af[4], bf[4];
#pragma unroll
    for (int mi = 0; mi < 4; mi++) af[mi] = rdfrag(pb, wm + mi * 16 + ar);
#pragma unroll
    for (int ni = 0; ni < 4; ni++) bf[ni] = rdfrag(pb + 16384, wn + ni * 16 + ar);
    GLGKM0();                    // frags in regs
    GBAR();                      // ALL waves done reading buf p
    const int kt2 = (X + 2 < 8) ? X + 2 : X;   // tail: benign same-data re-stage
    stage(kt2, p);               // overwrite buf p with tile X+2
    __builtin_amdgcn_s_setprio(1);
#pragma unroll
    for (int mi = 0; mi < 4; mi++)
#pragma unroll
      for (int ni = 0; ni < 4; ni++)
        acc[mi][ni] = __builtin_amdgcn_mfma_scale_f32_16x16x128_f8f6f4(
            af[mi], bf[ni], acc[mi][ni], 0, 0, 0, 127u, 0, 127u);
    __builtin_amdgcn_s_setprio(0);
    GVM8();                      // tile X+1 landed; X+2 stays in flight
    GBAR();
  }

  // ---- epilogue: LDS repack -> full-line coalesced stores (verified R4/R6/R7) ----
  asm volatile("s_waitcnt vmcnt(0)" ::: "memory");
  __syncthreads();
  const int os = n0 >> 10;
  unsigned short* Cp = (os == 0) ? C0 : ((os == 1) ? C1 : C2);
  const int colbase = n0 & (DIM - 1);
  unsigned short* lt = (unsigned short*)lds;       // [32][136] bf16 repack tile
  const int lrw = (wave >> 1) * 16 + aq * 4;       // + rr -> LDS row 0..31
  const int colc0 = (wave & 1) * 64;
  const int lrow = t >> 3;                         // 32 rows x 8 thr
  const int cseg = (t & 7) * 16;                   // 16 bf16 = 32B per thread
  const size_t grb = (size_t)(m0 + (lrow >> 4) * 64 + (lrow & 15)) * DIM + colbase + cseg;
#pragma unroll
  for (int mi = 0; mi < 4; mi++){
#pragma unroll
    for (int ni = 0; ni < 4; ni++){
      const int colc = colc0 + ni * 16 + ar;
#pragma unroll
      for (int rr = 0; rr < 4; rr++)
        lt[(lrw + rr) * 136 + colc] = f2bf(acc[mi][ni][rr] * 0.03125f);
    }
    __syncthreads();
    uint4 v0 = *(const uint4*)&lt[lrow * 136 + cseg];
    uint4 v1 = *(const uint4*)&lt[lrow * 136 + cseg + 8];
    *(uint4*)(Cp + grb + (size_t)mi * 16 * DIM) = v0;
    *(uint4*)(Cp + grb + (size_t)mi * 16 * DIM + 8) = v1;
    __syncthreads();
  }
}

// ---- top-64 select: one row per WAVE. Exact 2-pass radix-select on bf16
// sortable keys (per-wave LDS histograms); pipelined fp32-exact fixup;
// 16B loads; HW v_cvt_pk_fp8_f32 packed output. Verified R4/R5/R6/R7. ----
__global__ __launch_bounds__(256) void select_k(
  const unsigned short* __restrict__ gate_pre, const unsigned short* __restrict__ mag_pre,
  const float* __restrict__ x, const float* __restrict__ gW, const float* __restrict__ gb,
  unsigned char* __restrict__ xg8)
{
  __shared__ int   s_h  [4][256];
  __shared__ int   s_cnt[4];
  __shared__ int   s_idx[4][MAXC];
  __shared__ float s_ex [4][MAXC];
  __shared__ int   s_res[4][MAXC];

  const int t = threadIdx.x;
  const int lane = t & 63, wave = t >> 6;
  const int row = blockIdx.x * 4 + wave;
  const size_t rb = (size_t)row * DIM;

  // 16 elems/lane; dim(e) = (e>>3)*512 + lane*8 + (e&7)
  uint4 ga = *(const uint4*)(gate_pre + rb + lane * 8);
  uint4 gB = *(const uint4*)(gate_pre + rb + 512 + lane * 8);
  float4 xa0 = *(const float4*)(x + rb + lane * 8);
  float4 xa1 = *(const float4*)(x + rb + lane * 8 + 4);
  float4 xb0 = *(const float4*)(x + rb + 512 + lane * 8);
  float4 xb1 = *(const float4*)(x + rb + 512 + lane * 8 + 4);
  uint4 ma = *(const uint4*)(mag_pre + rb + lane * 8);
  uint4 mb = *(const uint4*)(mag_pre + rb + 512 + lane * 8);

  unsigned gw[8] = {ga.x, ga.y, ga.z, ga.w, gB.x, gB.y, gB.z, gB.w};
  unsigned mw[8] = {ma.x, ma.y, ma.z, ma.w, mb.x, mb.y, mb.z, mb.w};
  float vg[16], vm[16];
  unsigned kk[16];
#pragma unroll
  for (int j = 0; j < 8; j++){
    unsigned w = gw[j];
    vg[2*j]   = __uint_as_float(w << 16);
    vg[2*j+1] = __uint_as_float(w & 0xFFFF0000u);
    unsigned lo = w & 0xFFFFu, hi = w >> 16;
    kk[2*j]   = (lo & 0x8000u) ? (~lo & 0xFFFFu) : (lo | 0x8000u);
    kk[2*j+1] = (hi & 0x8000u) ? (~hi & 0xFFFFu) : (hi | 0x8000u);
    unsigned m = mw[j];
    vm[2*j]   = __uint_as_float(m << 16);
    vm[2*j+1] = __uint_as_float(m & 0xFFFF0000u);
  }
  float vx[16] = {xa0.x, xa0.y, xa0.z, xa0.w, xa1.x, xa1.y, xa1.z, xa1.w,
                  xb0.x, xb0.y, xb0.z, xb0.w, xb1.x, xb1.y, xb1.z, xb1.w};

  if (lane == 0) s_cnt[wave] = 0;

  // find bin b (0..255) with C(b) < rk <= C(b)+hist[b]; C = count strictly above
  auto findbin = [&](int rk, int &bout, int &Cout){
    int c0 = s_h[wave][lane*4+0], c1 = s_h[wave][lane*4+1];
    int c2 = s_h[wave][lane*4+2], c3 = s_h[wave][lane*4+3];
    int sl = c0 + c1 + c2 + c3;
    int tt = sl;
#pragma unroll
    for (int m = 1; m < 64; m <<= 1){
      int u = __shfl(tt, lane + m);
      if (lane + m < 64) tt += u;
    }
    int ab = tt - sl;                 // sum over lanes above (higher bins)
    int bb = -1, CC = 0;
    int a3 = ab;       if (a3 < rk && rk <= a3 + c3){ bb = lane*4+3; CC = a3; }
    int a2 = ab + c3;  if (bb < 0 && a2 < rk && rk <= a2 + c2){ bb = lane*4+2; CC = a2; }
    int a1 = a2 + c2;  if (bb < 0 && a1 < rk && rk <= a1 + c1){ bb = lane*4+1; CC = a1; }
    int a0 = a1 + c1;  if (bb < 0 && a0 < rk && rk <= a0 + c0){ bb = lane*4+0; CC = a0; }
    unsigned long long mk = __ballot(bb >= 0);
    int src = (int)__ffsll(mk) - 1;
    bout = __shfl(bb, src); Cout = __shfl(CC, src);
  };

  // pass 1: high byte
  s_h[wave][lane*4+0] = 0; s_h[wave][lane*4+1] = 0;
  s_h[wave][lane*4+2] = 0; s_h[wave][lane*4+3] = 0;
  lds_fence();
#pragma unroll
  for (int e = 0; e < 16; e++) atomicAdd(&s_h[wave][kk[e] >> 8], 1);
  lds_fence();
  int b1, C1; findbin(64, b1, C1);

  // pass 2: low byte within bin b1
  s_h[wave][lane*4+0] = 0; s_h[wave][lane*4+1] = 0;
  s_h[wave][lane*4+2] = 0; s_h[wave][lane*4+3] = 0;
  lds_fence();
#pragma unroll
  for (int e = 0; e < 16; e++)
    if ((int)(kk[e] >> 8) == b1) atomicAdd(&s_h[wave][kk[e] & 255u], 1);
  lds_fence();
  int b2, C2; findbin(64 - C1, b2, C2);

  unsigned tkey = ((unsigned)b1 << 8) | (unsigned)b2;
  unsigned hthr = (tkey & 0x8000u) ? (tkey & 0x7FFFu) : (~tkey & 0xFFFFu);
  const float thr = bf2f((unsigned short)hthr);
  const float cl = thr - MARGIN, ch = thr + MARGIN;

  int n1 = 0;
#pragma unroll
  for (int e = 0; e < 16; e++) n1 += (vg[e] > ch) ? 1 : 0;
#pragma unroll
  for (int m = 32; m; m >>= 1) n1 += __shfl_xor(n1, m);
  const int s = 64 - n1;

  lds_fence();
#pragma unroll
  for (int e = 0; e < 16; e++){
    float vv = vg[e];
    if (vv >= cl && vv <= ch){
      int p = atomicAdd(&s_cnt[wave], 1);
      if (p < MAXC) s_idx[wave][p] = (e >> 3) * 512 + lane * 8 + (e & 7);
    }
  }
  lds_fence();
  int namb = s_cnt[wave]; if (namb > MAXC) namb = MAXC;

  // pipelined exact fp32 recompute of ambiguous dims
  const int o0 = lane * 8, o1 = lane * 8 + 4, o2 = 512 + lane * 8, o3 = 512 + lane * 8 + 4;
  float4 w0, w1, w2, w3;
  int dcur = 0;
  if (namb > 0){
    dcur = s_idx[wave][0];
    const float* wr0 = gW + (size_t)dcur * DIM;
    w0 = *(const float4*)(wr0 + o0); w1 = *(const float4*)(wr0 + o1);
    w2 = *(const float4*)(wr0 + o2); w3 = *(const float4*)(wr0 + o3);
  }
  for (int i = 0; i < namb; i++){
    float4 c0 = w0, c1 = w1, c2 = w2, c3 = w3;
    int dn = 0;
    if (i + 1 < namb){
      dn = s_idx[wave][i + 1];
      const float* wr2 = gW + (size_t)dn * DIM;
      w0 = *(const float4*)(wr2 + o0); w1 = *(const float4*)(wr2 + o1);
      w2 = *(const float4*)(wr2 + o2); w3 = *(const float4*)(wr2 + o3);
    }
    float p = 0.f;
    p = fmaf(vx[0], c0.x, p);  p = fmaf(vx[1], c0.y, p);
    p = fmaf(vx[2], c0.z, p);  p = fmaf(vx[3], c0.w, p);
    p = fmaf(vx[4], c1.x, p);  p = fmaf(vx[5], c1.y, p);
    p = fmaf(vx[6], c1.z, p);  p = fmaf(vx[7], c1.w, p);
    p = fmaf(vx[8], c2.x, p);  p = fmaf(vx[9], c2.y, p);
    p = fmaf(vx[10], c2.z, p); p = fmaf(vx[11], c2.w, p);
    p = fmaf(vx[12], c3.x, p); p = fmaf(vx[13], c3.y, p);
    p = fmaf(vx[14], c3.z, p); p = fmaf(vx[15], c3.w, p);
#pragma unroll
    for (int m = 32; m; m >>= 1) p += __shfl_xor(p, m);
    if (lane == 0) s_ex[wave][i] = p + gb[dcur];
    dcur = dn;
  }
  lds_fence();

  if (lane < namb){
    float e = s_ex[wave][lane]; int d = s_idx[wave][lane];
    int rank = 0;
    for (int j = 0; j < namb; j++){
      float ej = s_ex[wave][j]; int dj = s_idx[wave][j];
      if (ej > e || (ej == e && dj < d)) rank++;
    }
    s_res[wave][lane] = (rank < s && e > 0.f) ? 1 : 0;
  }
  lds_fence();

  // per-lane in-band membership/result masks (static vals indexing, rule #20)
  unsigned inb = 0, rsm = 0;
  for (int i = 0; i < namb; i++){
    int d = s_idx[wave][i];
    if (((d & 511) >> 3) == lane){
      int e = (d >> 9) * 8 + (d & 7);
      inb |= 1u << e;
      if (s_res[wave][i]) rsm |= 1u << e;
    }
  }

  float vals[16];
#pragma unroll
  for (int e = 0; e < 16; e++){
    float mv = (vm[e] > 0.f) ? vm[e] : 0.f;       // relu, -0 -> +0
    float v = (vg[e] > ch && vg[e] > 0.f) ? mv : 0.f;
    if ((inb >> e) & 1u) v = ((rsm >> e) & 1u) ? mv : 0.f;
    vals[e] = v;
  }

  unsigned pk[4];
#pragma unroll
  for (int q = 0; q < 4; q++){
    unsigned a = 0, b = 0;
    asm volatile("v_cvt_pk_fp8_f32 %0, %1, %2" : "+v"(a) : "v"(vals[4*q+0]), "v"(vals[4*q+1]));
    asm volatile("v_cvt_pk_fp8_f32 %0, %1, %2" : "+v"(b) : "v"(vals[4*q+2]), "v"(vals[4*q+3]));
    pk[q] = (a & 0xFFFFu) | (b << 16);
  }
  uint2 st0; st0.x = pk[0]; st0.y = pk[1];
  uint2 st1; st1.x = pk[2]; st1.y = pk[3];
  *(uint2*)(xg8 + rb + lane * 8) = st0;
  *(uint2*)(xg8 + rb + 512 + lane * 8) = st1;
}

// ------- epilogue: 4 rows/block, prev row + inverse-norms carried in registers -------
__global__ __launch_bounds__(256) void epilogue_k(
  const unsigned short* __restrict__ q_pre, const unsigned short* __restrict__ k_pre,
  const unsigned short* __restrict__ p_pre, float* __restrict__ out)
{
  const int r0 = blockIdx.x * 4;
  const int t = threadIdx.x;
  const int lane = t & 63, wave = t >> 6;
  __shared__ float red[16];

  const int rp = (r0 == 0) ? 0 : r0 - 1;
  float vqp[4], vkp[4], vpp[4];
  {
    ushort4 uq = *(const ushort4*)(q_pre + (size_t)rp * DIM + 4*t);
    ushort4 uk = *(const ushort4*)(k_pre + (size_t)rp * DIM + 4*t);
    ushort4 up = *(const ushort4*)(p_pre + (size_t)rp * DIM + 4*t);
    vqp[0]=bf2f(uq.x); vqp[1]=bf2f(uq.y); vqp[2]=bf2f(uq.z); vqp[3]=bf2f(uq.w);
    vkp[0]=bf2f(uk.x); vkp[1]=bf2f(uk.y); vkp[2]=bf2f(uk.z); vkp[3]=bf2f(uk.w);
    vpp[0]=bf2f(up.x); vpp[1]=bf2f(up.y); vpp[2]=bf2f(up.z); vpp[3]=bf2f(up.w);
  }
  float aq = 0.f, ak = 0.f;
#pragma unroll
  for (int j = 0; j < 4; j++){ aq = fmaf(vqp[j], vqp[j], aq); ak = fmaf(vkp[j], vkp[j], ak); }
#pragma unroll
  for (int m = 32; m; m >>= 1){ aq += __shfl_xor(aq, m); ak += __shfl_xor(ak, m); }
  if (lane == 0){ red[wave] = aq; red[4 + wave] = ak; }
  __syncthreads();
  float rqp = 1.f / fmaxf(sqrtf(red[0] + red[1] + red[2] + red[3]), 1e-12f);
  float rkp = 1.f / fmaxf(sqrtf(red[4] + red[5] + red[6] + red[7]), 1e-12f);
  __syncthreads();

  for (int rr = 0; rr < 4; rr++){
    const int r = r0 + rr;
    float vqc[4], vkc[4], vpc[4];
    {
      ushort4 uq = *(const ushort4*)(q_pre + (size_t)r * DIM + 4*t);
      ushort4 uk = *(const ushort4*)(k_pre + (size_t)r * DIM + 4*t);
      ushort4 up = *(const ushort4*)(p_pre + (size_t)r * DIM + 4*t);
      vqc[0]=bf2f(uq.x); vqc[1]=bf2f(uq.y); vqc[2]=bf2f(uq.z); vqc[3]=bf2f(uq.w);
      vkc[0]=bf2f(uk.x); vkc[1]=bf2f(uk.y); vkc[2]=bf2f(uk.z); vkc[3]=bf2f(uk.w);
      vpc[0]=bf2f(up.x); vpc[1]=bf2f(up.y); vpc[2]=bf2f(up.z); vpc[3]=bf2f(up.w);
    }
    const bool seg = (r & (SEQ - 1)) == 0;
    float aqc = 0.f, akc = 0.f;
#pragma unroll
    for (int j = 0; j < 4; j++){ aqc = fmaf(vqc[j], vqc[j], aqc); akc = fmaf(vkc[j], vkc[j], akc); }
    float dsum = 0.f;
    if (!seg){
#pragma unroll
      for (int j = 0; j < 2; j++){
        float ax = vpp[2*j], ay = vpp[2*j+1], bx = vpc[2*j], by = vpc[2*j+1];
        float ia = 1.f / fmaxf(sqrtf(ax * ax + ay * ay), 1e-12f);
        float ib = 1.f / fmaxf(sqrtf(bx * bx + by * by), 1e-12f);
        ax *= ia; ay *= ia; bx *= ib; by *= ib;
        float cross = ax * by - ay * bx;
        float dot = fminf(fmaxf(ax * bx + ay * by, -1.f), 1.f);
        dsum += fabsf(atan2f(cross, dot)) * 0.3183098861837907f;
      }
    }
#pragma unroll
    for (int m = 32; m; m >>= 1){
      aqc += __shfl_xor(aqc, m); akc += __shfl_xor(akc, m); dsum += __shfl_xor(dsum, m);
    }
    if (lane == 0){ red[wave] = aqc; red[4 + wave] = akc; red[8 + wave] = dsum; }
    __syncthreads();
    float rqc = 1.f / fmaxf(sqrtf(red[0] + red[1] + red[2] + red[3]), 1e-12f);
    float rkc = 1.f / fmaxf(sqrtf(red[4] + red[5] + red[6] + red[7]), 1e-12f);
    if (!seg){
      float tw = 0.f;
#pragma unroll
      for (int j = 0; j < 4; j++){
        float m = (vqc[j] * rqc) * (vkp[j] * rkp) - (vqp[j] * rqp) * (vkc[j] * rkc);
        tw = fmaf(m, m, tw);
      }
#pragma unroll
      for (int m = 32; m; m >>= 1) tw += __shfl_xor(tw, m);
      if (lane == 0) red[12 + wave] = tw;
      __syncthreads();
      if (t == 0){
        float dtot = red[8] + red[9] + red[10] + red[11];
        float twt = red[12] + red[13] + red[14] + red[15];
        out[r] = 0.5f * tanhf(sqrtf(twt)) + 0.5f * (dtot * (1.f / 512.f));
      }
    } else {
      if (t == 0) out[r] = 0.f;
    }
    __syncthreads();
#pragma unroll
    for (int j = 0; j < 4; j++){ vqp[j] = vqc[j]; vkp[j] = vkc[j]; vpp[j] = vpc[j]; }
    rqp = rqc; rkp = rkc;
  }
}

extern "C" void kernel_launch(void* const* d_in, const int* in_sizes, int n_in,
                              void* d_out, int out_size, void* d_ws, size_t ws_size,
                              hipStream_t stream)
{
  const float* x       = (const float*)d_in[0];
  const float* gate_W  = (const float*)d_in[1];
  const float* gate_b  = (const float*)d_in[2];
  const float* mag_W   = (const float*)d_in[3];
  const float* mag_b   = (const float*)d_in[4];
  const float* Wq      = (const float*)d_in[5];
  const float* Wk      = (const float*)d_in[6];
  const float* phase_W = (const float*)d_in[7];
  float* out = (float*)d_out;

  char* ws = (char*)d_ws;
  unsigned short* xbf = (unsigned short*)ws;                    // 32 MB @0 (reused as xg8)
  unsigned short* wbf = (unsigned short*)(ws + 33554432);       //  4 MB @32M: [gate;mag] bf16
  unsigned char*  wf8 = (unsigned char*)(ws + 37748736);        //  3 MB @36M: [q;k;p] fp8 x32
  unsigned short* gate_pre = (unsigned short*)(ws + 41943040);  // 32 MB @40M (reused as q_pre)
  unsigned short* mag_pre  = (unsigned short*)(ws + 75497472);  // 32 MB @72M (reused as k_pre)
  unsigned short* p_pre    = (unsigned short*)(ws + 109051904); // 32 MB @104M
  unsigned short* q_pre = gate_pre;
  unsigned short* k_pre = mag_pre;

  static bool attr_set = false;
  if (!attr_set){
    hipFuncSetAttribute((const void*)gemm_bt,
                        hipFuncAttributeMaxDynamicSharedMemorySize, 65536);
    hipFuncSetAttribute((const void*)gemm8,
                        hipFuncAttributeMaxDynamicSharedMemorySize, 65536);
    attr_set = true;
  }

  dim3 b256(256);
  cvt_all<<<dim3(1024, 21), b256, 0, stream>>>(x, gate_W, mag_W, Wq, Wk, phase_W,
                                               xbf, wbf, wf8);

  // gate+mag fused bf16 GEMM (N=2048): 128^2 tiles, dbuf LDS, 2 blocks/CU
  gemm_bt<<<dim3(2048), b256, 65536, stream>>>(xbf, wbf, gate_b, mag_b,
                                               gate_pre, mag_pre);

  unsigned char* xg8 = (unsigned char*)xbf;   // xbf no longer needed
  select_k<<<ROWS / 4, b256, 0, stream>>>(gate_pre, mag_pre, x, gate_W, gate_b, xg8);

  // q+k+phase MX-fp8 GEMM (N=3072): 128^2 tiles, dbuf LDS, 2 blocks/CU
  gemm8<<<dim3(3072), b256, 65536, stream>>>(xg8, wf8, q_pre, k_pre, p_pre);

  epilogue_k<<<ROWS / 4, b256, 0, stream>>>(q_pre, k_pre, p_pre, out);
}

// Round 9
// 361.269 us; speedup vs baseline: 1.0558x; 1.0558x over previous
//
#include <hip/hip_runtime.h>
#include <math.h>

#define DIM 1024
#define ROWS 16384
#define SEQ 4096
#define MARGIN 0.012f
#define MAXC 24

typedef __bf16 v8bf __attribute__((ext_vector_type(8)));
typedef float v4f __attribute__((ext_vector_type(4)));
typedef int v8i __attribute__((ext_vector_type(8)));

__device__ __forceinline__ unsigned short f2bf(float f){
  unsigned u = __float_as_uint(f);
  u = u + 0x7FFFu + ((u >> 16) & 1u);   // RNE
  return (unsigned short)(u >> 16);
}
__device__ __forceinline__ float bf2f(unsigned short h){
  return __uint_as_float(((unsigned)h) << 16);
}
__device__ __forceinline__ unsigned short relu_bf(unsigned short h){
  return (h & 0x8000u) ? (unsigned short)0 : h;
}
// SW float -> OCP e4m3fn (RNE, saturating)
__device__ __forceinline__ unsigned f2fp8(float f){
  float a = fabsf(f);
  unsigned sign = (__float_as_uint(f) >> 24) & 0x80u;
  if (a >= 448.f) return sign | 0x7Eu;
  if (a < 0.015625f){                       // subnormal, step 2^-9
    int k = (int)rintf(a * 512.f);          // RNE
    if (k >= 8) return sign | 0x08u;
    return sign | (unsigned)k;
  }
  unsigned u = __float_as_uint(a);
  u += 0x7FFFFu + ((u >> 20) & 1u);         // RNE at 3 mantissa bits
  int e = (int)((u >> 23) & 0xFFu) - 127;
  unsigned m = (u >> 20) & 7u;
  if (e > 8) return sign | 0x7Eu;
  return sign | ((unsigned)(e + 7) << 3) | m;
}
__device__ __forceinline__ void lds_fence(){
  __asm__ volatile("s_waitcnt lgkmcnt(0)" ::: "memory");
}

// ---- fused convert: y<16 x->bf16; y=16,17 gate/mag W->bf16; y=18..20 q/k/p W->fp8(x32) ----
__global__ __launch_bounds__(256) void cvt_all(
    const float* __restrict__ x,
    const float* __restrict__ w0, const float* __restrict__ w1,
    const float* __restrict__ w2, const float* __restrict__ w3,
    const float* __restrict__ w4,
    unsigned short* __restrict__ xbf, unsigned short* __restrict__ wbf,
    unsigned char* __restrict__ wf8){
  const int y = blockIdx.y;
  int i = (blockIdx.x * 256 + threadIdx.x) * 4;
  if (y < 16){
    const float* s = x + ((size_t)y << 20);
    float4 f = *(const float4*)(s + i);
    ushort4 o; o.x = f2bf(f.x); o.y = f2bf(f.y); o.z = f2bf(f.z); o.w = f2bf(f.w);
    *(ushort4*)(xbf + ((size_t)y << 20) + i) = o;
  } else if (y < 18){
    const float* s = (y == 16) ? w0 : w1;
    float4 f = *(const float4*)(s + i);
    ushort4 o; o.x = f2bf(f.x); o.y = f2bf(f.y); o.z = f2bf(f.z); o.w = f2bf(f.w);
    *(ushort4*)(wbf + ((size_t)(y - 16) << 20) + i) = o;
  } else {
    const float* s = (y == 18) ? w2 : ((y == 19) ? w3 : w4);
    float4 f = *(const float4*)(s + i);
    unsigned u = f2fp8(f.x * 32.f) | (f2fp8(f.y * 32.f) << 8) |
                 (f2fp8(f.z * 32.f) << 16) | (f2fp8(f.w * 32.f) << 24);
    *(unsigned*)(wf8 + ((size_t)(y - 18) << 20) + i) = u;
  }
}

#define GBAR() asm volatile("s_barrier" ::: "memory")
#define GLGKM0() { asm volatile("s_waitcnt lgkmcnt(0)" ::: "memory"); __builtin_amdgcn_sched_barrier(0); }
#define GVM4() asm volatile("s_waitcnt vmcnt(4)" ::: "memory")
#define GVM8() asm volatile("s_waitcnt vmcnt(8)" ::: "memory")

#define GLD1(srcp, dsto) __builtin_amdgcn_global_load_lds( \
    (const __attribute__((address_space(1))) void*)(srcp), \
    (__attribute__((address_space(3))) void*)(lds + (dsto)), 16, 0, 0)

// =====================================================================
// GEMM1 (bf16), R9: R7-verified 256x256/8-wave skeleton with balanced
// per-phase ds_reads (8/4/8/4, was 12/8/4/0) and both B(X+2) half-stages
// moved to g3 (after the g2-end barrier, which provably follows all
// waves' b0/b1 consumption -> old mid-loop lgkm fence dropped).
// vmcnt invariant unchanged: 8 loads/K-tile, vmcnt(4) at g3-end leaves
// exactly the B(X+2) pair in flight -> A(X+1) landed. Same K order.
// =====================================================================
__global__ __launch_bounds__(512, 2) void gemm_bt(
    const unsigned short* __restrict__ A, const unsigned short* __restrict__ B,
    const float* __restrict__ bias0, const float* __restrict__ bias1,
    unsigned short* __restrict__ C0, unsigned short* __restrict__ C1)
{
  extern __shared__ unsigned char lds[];
  const int t = threadIdx.x;
  const int lane = t & 63, wave = t >> 6;
  const int wr = wave >> 2, wc = wave & 3;          // 2 (M) x 4 (N) wave grid
  const int bid = blockIdx.x;
  const int swz = (bid & 7) * 64 + (bid >> 3);      // XCD swizzle, 512 % 8 == 0
  const int m0 = (swz & 63) * 256;
  const int n0 = (swz >> 6) * 256;

  // staging inverse-swizzle: chunk (h,i,t) -> global (row,col) element offset
  int offv[4];
#pragma unroll
  for (int h = 0; h < 2; h++)
#pragma unroll
    for (int i = 0; i < 2; i++){
      int o = h * 16384 + i * 8192 + t * 16;
      int u = o ^ (((o >> 9) & 1) << 5);
      int r = ((u >> 11) << 4) | ((u >> 6) & 15);
      int c = (((u >> 10) & 1) << 5) | ((u & 63) >> 1);
      offv[h * 2 + i] = r * 1024 + c;
    }
  const int off00 = offv[0], off01 = offv[1], off10 = offv[2], off11 = offv[3];
  const unsigned short* Ab = A + ((size_t)m0 << 10);
  const unsigned short* Bb = B + ((size_t)n0 << 10);

  // ds_read addressing: swizzled byte offset for (frag row block, lane)
  const int laneterm = (lane & 15) * 64 + (((lane >> 4) * 16) ^ (((lane >> 3) & 1) * 32));
  const int aBase = wr * 16384 + laneterm;            // + mi*2048 + k*1024 (+buf*65536)
  const int bBase = 32768 + wc * 8192 + laneterm;     // + ni*2048 + k*1024

  auto stageA = [&](int h, int kt, int pp){
    const int o0 = h ? off10 : off00, o1 = h ? off11 : off01;
    GLD1(Ab + o0 + kt * 64, pp * 65536 + h * 16384 + t * 16);
    GLD1(Ab + o1 + kt * 64, pp * 65536 + h * 16384 + 8192 + t * 16);
  };
  auto stageB = [&](int h, int kt, int pp){
    const int o0 = h ? off10 : off00, o1 = h ? off11 : off01;
    GLD1(Bb + o0 + kt * 64, pp * 65536 + 32768 + h * 16384 + t * 16);
    GLD1(Bb + o1 + kt * 64, pp * 65536 + 32768 + h * 16384 + 8192 + t * 16);
  };

  v4f acc[8][4];
#pragma unroll
  for (int i = 0; i < 8; i++)
#pragma unroll
    for (int j = 0; j < 4; j++) acc[i][j] = v4f{0.f, 0.f, 0.f, 0.f};

  // prologue: B(0), A(0) -> buf0; B(1) -> buf1  (12 loads/thread)
  stageB(0, 0, 0); stageB(1, 0, 0);
  stageA(0, 0, 0); stageA(1, 0, 0);
  stageB(0, 1, 1); stageB(1, 1, 1);
  GVM4();                        // first 8 landed: tile 0 complete; B(1) in flight
  GBAR();

  int p = 0;
  for (int X = 0; X < 16; X++, p ^= 1){
    const int pb = p * 65536;
    const int ktA = (X + 1 < 16) ? X + 1 : 15;   // tail: benign re-issue
    const int ktB = (X + 2 < 16) ? X + 2 : X;    // tail: benign re-issue (same data)
    v8bf a0[8], a1[8], b0[4], b1[4];

    // ---- g0: a0[0..3]+b0 (8 reads) + stage Ah0(X+1) ----
#pragma unroll
    for (int mi = 0; mi < 4; mi++) a0[mi] = *(const v8bf*)(lds + pb + aBase + mi * 2048);
#pragma unroll
    for (int ni = 0; ni < 4; ni++) b0[ni] = *(const v8bf*)(lds + pb + bBase + ni * 2048);
    stageA(0, ktA, p ^ 1);
    GBAR();
    __builtin_amdgcn_s_setprio(1);
#pragma unroll
    for (int mi = 0; mi < 4; mi++)
#pragma unroll
      for (int ni = 0; ni < 4; ni++)
        acc[mi][ni] = __builtin_amdgcn_mfma_f32_16x16x32_bf16(a0[mi], b0[ni], acc[mi][ni], 0, 0, 0);
    __builtin_amdgcn_s_setprio(0);
    GBAR();

    // ---- g1: a0[4..7] (4 reads) + stage Ah1(X+1) ----
#pragma unroll
    for (int mi = 4; mi < 8; mi++) a0[mi] = *(const v8bf*)(lds + pb + aBase + mi * 2048);
    stageA(1, ktA, p ^ 1);
    GBAR();
    __builtin_amdgcn_s_setprio(1);
#pragma unroll
    for (int mi = 0; mi < 4; mi++)
#pragma unroll
      for (int ni = 0; ni < 4; ni++)
        acc[4 + mi][ni] = __builtin_amdgcn_mfma_f32_16x16x32_bf16(a0[4 + mi], b0[ni], acc[4 + mi][ni], 0, 0, 0);
    __builtin_amdgcn_s_setprio(0);
    GBAR();

    // ---- g2: a1[0..3]+b1 (8 reads), no stage ----
#pragma unroll
    for (int mi = 0; mi < 4; mi++) a1[mi] = *(const v8bf*)(lds + pb + aBase + 1024 + mi * 2048);
#pragma unroll
    for (int ni = 0; ni < 4; ni++) b1[ni] = *(const v8bf*)(lds + pb + bBase + 1024 + ni * 2048);
    GBAR();
    __builtin_amdgcn_s_setprio(1);
#pragma unroll
    for (int mi = 0; mi < 4; mi++)
#pragma unroll
      for (int ni = 0; ni < 4; ni++)
        acc[mi][ni] = __builtin_amdgcn_mfma_f32_16x16x32_bf16(a1[mi], b1[ni], acc[mi][ni], 0, 0, 0);
    __builtin_amdgcn_s_setprio(0);
    GBAR();
    // g2-end barrier: all waves' b0/b1 reads of buf p consumed -> B overwrite safe

    // ---- g3: a1[4..7] (4 reads) + stage Bh0+Bh1(X+2) -> buf p ----
#pragma unroll
    for (int mi = 4; mi < 8; mi++) a1[mi] = *(const v8bf*)(lds + pb + aBase + 1024 + mi * 2048);
    stageB(0, ktB, p);
    stageB(1, ktB, p);
    GBAR();
    __builtin_amdgcn_s_setprio(1);
#pragma unroll
    for (int mi = 0; mi < 4; mi++)
#pragma unroll
      for (int ni = 0; ni < 4; ni++)
        acc[4 + mi][ni] = __builtin_amdgcn_mfma_f32_16x16x32_bf16(a1[4 + mi], b1[ni], acc[4 + mi][ni], 0, 0, 0);
    __builtin_amdgcn_s_setprio(0);
    GVM4();                  // A(X+1) landed; B(X+2) may stay in flight
    GBAR();
  }

  // ---- epilogue: LDS repack -> full-line coalesced stores ----
  asm volatile("s_waitcnt vmcnt(0)" ::: "memory");
  __syncthreads();

  const int os = n0 >> 10;
  unsigned short* Cp = (os == 0) ? C0 : C1;
  const float* bp = (os == 0) ? bias0 : bias1;
  const int colbase = n0 & (DIM - 1);
  unsigned short* lt = (unsigned short*)lds;       // [32][264] bf16 repack tile
  const int ar = lane & 15, aq = lane >> 4;
  const int lrw = wr * 16 + aq * 4;                // + rr -> LDS row 0..31
  const int lrow = t >> 4;                         // read-back: 32 rows x 16 thr
  const int cseg = (t & 15) * 16;                  // 16 bf16 = 32B per thread
  const size_t grb = (size_t)(m0 + (lrow >> 4) * 128 + (lrow & 15)) * DIM + colbase + cseg;
  float bv[4];
#pragma unroll
  for (int ni = 0; ni < 4; ni++) bv[ni] = bp[colbase + wc * 64 + ni * 16 + ar];
#pragma unroll
  for (int mi = 0; mi < 8; mi++){
#pragma unroll
    for (int ni = 0; ni < 4; ni++){
      const int colc = wc * 64 + ni * 16 + ar;
#pragma unroll
      for (int rr = 0; rr < 4; rr++)
        lt[(lrw + rr) * 264 + colc] = f2bf(acc[mi][ni][rr] + bv[ni]);
    }
    __syncthreads();
    uint4 v0 = *(const uint4*)&lt[lrow * 264 + cseg];
    uint4 v1 = *(const uint4*)&lt[lrow * 264 + cseg + 8];
    *(uint4*)(Cp + grb + (size_t)mi * 16 * DIM) = v0;
    *(uint4*)(Cp + grb + (size_t)mi * 16 * DIM + 8) = v1;
    __syncthreads();
  }
  asm volatile("s_waitcnt vmcnt(0)" ::: "memory");
}

// =====================================================================
// GEMM2 (MX-fp8): 128x128 tile, 4 waves, 64KB dbuf LDS, 2 blocks/CU.
// Verified R7/R8. m-fast XCD supertiling; XOR-swizzled staging + pair reads.
// =====================================================================
__global__ __launch_bounds__(256, 2) void gemm8(
    const unsigned char* __restrict__ A, const unsigned char* __restrict__ B,
    unsigned short* __restrict__ C0, unsigned short* __restrict__ C1,
    unsigned short* __restrict__ C2)
{
  extern __shared__ unsigned char lds[];
  const int t = threadIdx.x;
  const int lane = t & 63, wave = t >> 6;
  const int wm = (wave >> 1) * 64;                  // 2(M) x 2(N) wave grid
  const int wn = (wave & 1) * 64;
  const int ar = lane & 15, aq = lane >> 4;

  const int bid = blockIdx.x;                       // 3072 blocks
  const int loc = bid >> 3;                         // 384 per XCD
  const int m0 = ((bid & 7) * 16 + (loc & 15)) * 128;   // m-fast within XCD
  const int n0 = (loc >> 4) * 128;                  // n in [0,24)

  const unsigned char* Ab = A + ((size_t)m0 << 10);
  const unsigned char* Bb = B + ((size_t)n0 << 10);

  // staging: 4 chunks/thread per operand, inverse-swizzled global source
  int offb[4];
#pragma unroll
  for (int i = 0; i < 4; i++){
    int d = i * 4096 + t * 16;
    int row = d >> 7;
    offb[i] = row * 1024 + ((d & 127) ^ ((row & 7) << 4));
  }
  auto stage = [&](int kt, int p){                  // 8 GLDs/thread
#pragma unroll
    for (int i = 0; i < 4; i++)
      GLD1(Ab + offb[i] + kt * 128, p * 32768 + i * 4096 + t * 16);
#pragma unroll
    for (int i = 0; i < 4; i++)
      GLD1(Bb + offb[i] + kt * 128, p * 32768 + 16384 + i * 4096 + t * 16);
  };
  // fragment read: tile row r, K-bytes aq*32..+32, swizzled pair read
  auto rdfrag = [&](int boff, int r) -> v8i {
    int base = boff + r * 128 + ((aq * 32) ^ ((r & 7) << 4));
    int4 lo = *(const int4*)(lds + base);
    int4 hi = *(const int4*)(lds + (base ^ 16));
    v8i v; v[0]=lo.x; v[1]=lo.y; v[2]=lo.z; v[3]=lo.w;
           v[4]=hi.x; v[5]=hi.y; v[6]=hi.z; v[7]=hi.w;
    return v;
  };

  v4f acc[4][4];
#pragma unroll
  for (int i = 0; i < 4; i++)
#pragma unroll
    for (int j = 0; j < 4; j++) acc[i][j] = v4f{0.f, 0.f, 0.f, 0.f};

  // prologue: tile0 -> buf0, tile1 -> buf1 (16 GLDs/thread)
  stage(0, 0); stage(1, 1);
  GVM8();                        // tile0 landed; tile1 in flight
  GBAR();

  for (int X = 0; X < 8; X++){
    const int p = X & 1, pb = p * 32768;
    v8i af[4], bf[4];
#pragma unroll
    for (int mi = 0; mi < 4; mi++) af[mi] = rdfrag(pb, wm + mi * 16 + ar);
#pragma unroll
    for (int ni = 0; ni < 4; ni++) bf[ni] = rdfrag(pb + 16384, wn + ni * 16 + ar);
    GLGKM0();                    // frags in regs
    GBAR();                      // ALL waves done reading buf p
    const int kt2 = (X + 2 < 8) ? X + 2 : X;   // tail: benign same-data re-stage
    stage(kt2, p);               // overwrite buf p with tile X+2
    __builtin_amdgcn_s_setprio(1);
#pragma unroll
    for (int mi = 0; mi < 4; mi++)
#pragma unroll
      for (int ni = 0; ni < 4; ni++)
        acc[mi][ni] = __builtin_amdgcn_mfma_scale_f32_16x16x128_f8f6f4(
            af[mi], bf[ni], acc[mi][ni], 0, 0, 0, 127u, 0, 127u);
    __builtin_amdgcn_s_setprio(0);
    GVM8();                      // tile X+1 landed; X+2 stays in flight
    GBAR();
  }

  // ---- epilogue: LDS repack -> full-line coalesced stores (verified R4/R6/R7) ----
  asm volatile("s_waitcnt vmcnt(0)" ::: "memory");
  __syncthreads();
  const int os = n0 >> 10;
  unsigned short* Cp = (os == 0) ? C0 : ((os == 1) ? C1 : C2);
  const int colbase = n0 & (DIM - 1);
  unsigned short* lt = (unsigned short*)lds;       // [32][136] bf16 repack tile
  const int lrw = (wave >> 1) * 16 + aq * 4;       // + rr -> LDS row 0..31
  const int colc0 = (wave & 1) * 64;
  const int lrow = t >> 3;                         // 32 rows x 8 thr
  const int cseg = (t & 7) * 16;                   // 16 bf16 = 32B per thread
  const size_t grb = (size_t)(m0 + (lrow >> 4) * 64 + (lrow & 15)) * DIM + colbase + cseg;
#pragma unroll
  for (int mi = 0; mi < 4; mi++){
#pragma unroll
    for (int ni = 0; ni < 4; ni++){
      const int colc = colc0 + ni * 16 + ar;
#pragma unroll
      for (int rr = 0; rr < 4; rr++)
        lt[(lrw + rr) * 136 + colc] = f2bf(acc[mi][ni][rr] * 0.03125f);
    }
    __syncthreads();
    uint4 v0 = *(const uint4*)&lt[lrow * 136 + cseg];
    uint4 v1 = *(const uint4*)&lt[lrow * 136 + cseg + 8];
    *(uint4*)(Cp + grb + (size_t)mi * 16 * DIM) = v0;
    *(uint4*)(Cp + grb + (size_t)mi * 16 * DIM + 8) = v1;
    __syncthreads();
  }
}

// ---- top-64 select: one row per WAVE. Exact 2-pass radix-select on bf16
// sortable keys (per-wave LDS histograms); pipelined fp32-exact fixup;
// 16B loads; HW v_cvt_pk_fp8_f32 packed output. Verified R4-R8. ----
__global__ __launch_bounds__(256) void select_k(
  const unsigned short* __restrict__ gate_pre, const unsigned short* __restrict__ mag_pre,
  const float* __restrict__ x, const float* __restrict__ gW, const float* __restrict__ gb,
  unsigned char* __restrict__ xg8)
{
  __shared__ int   s_h  [4][256];
  __shared__ int   s_cnt[4];
  __shared__ int   s_idx[4][MAXC];
  __shared__ float s_ex [4][MAXC];
  __shared__ int   s_res[4][MAXC];

  const int t = threadIdx.x;
  const int lane = t & 63, wave = t >> 6;
  const int row = blockIdx.x * 4 + wave;
  const size_t rb = (size_t)row * DIM;

  // 16 elems/lane; dim(e) = (e>>3)*512 + lane*8 + (e&7)
  uint4 ga = *(const uint4*)(gate_pre + rb + lane * 8);
  uint4 gB = *(const uint4*)(gate_pre + rb + 512 + lane * 8);
  float4 xa0 = *(const float4*)(x + rb + lane * 8);
  float4 xa1 = *(const float4*)(x + rb + lane * 8 + 4);
  float4 xb0 = *(const float4*)(x + rb + 512 + lane * 8);
  float4 xb1 = *(const float4*)(x + rb + 512 + lane * 8 + 4);
  uint4 ma = *(const uint4*)(mag_pre + rb + lane * 8);
  uint4 mb = *(const uint4*)(mag_pre + rb + 512 + lane * 8);

  unsigned gw[8] = {ga.x, ga.y, ga.z, ga.w, gB.x, gB.y, gB.z, gB.w};
  unsigned mw[8] = {ma.x, ma.y, ma.z, ma.w, mb.x, mb.y, mb.z, mb.w};
  float vg[16], vm[16];
  unsigned kk[16];
#pragma unroll
  for (int j = 0; j < 8; j++){
    unsigned w = gw[j];
    vg[2*j]   = __uint_as_float(w << 16);
    vg[2*j+1] = __uint_as_float(w & 0xFFFF0000u);
    unsigned lo = w & 0xFFFFu, hi = w >> 16;
    kk[2*j]   = (lo & 0x8000u) ? (~lo & 0xFFFFu) : (lo | 0x8000u);
    kk[2*j+1] = (hi & 0x8000u) ? (~hi & 0xFFFFu) : (hi | 0x8000u);
    unsigned m = mw[j];
    vm[2*j]   = __uint_as_float(m << 16);
    vm[2*j+1] = __uint_as_float(m & 0xFFFF0000u);
  }
  float vx[16] = {xa0.x, xa0.y, xa0.z, xa0.w, xa1.x, xa1.y, xa1.z, xa1.w,
                  xb0.x, xb0.y, xb0.z, xb0.w, xb1.x, xb1.y, xb1.z, xb1.w};

  if (lane == 0) s_cnt[wave] = 0;

  // find bin b (0..255) with C(b) < rk <= C(b)+hist[b]; C = count strictly above
  auto findbin = [&](int rk, int &bout, int &Cout){
    int c0 = s_h[wave][lane*4+0], c1 = s_h[wave][lane*4+1];
    int c2 = s_h[wave][lane*4+2], c3 = s_h[wave][lane*4+3];
    int sl = c0 + c1 + c2 + c3;
    int tt = sl;
#pragma unroll
    for (int m = 1; m < 64; m <<= 1){
      int u = __shfl(tt, lane + m);
      if (lane + m < 64) tt += u;
    }
    int ab = tt - sl;                 // sum over lanes above (higher bins)
    int bb = -1, CC = 0;
    int a3 = ab;       if (a3 < rk && rk <= a3 + c3){ bb = lane*4+3; CC = a3; }
    int a2 = ab + c3;  if (bb < 0 && a2 < rk && rk <= a2 + c2){ bb = lane*4+2; CC = a2; }
    int a1 = a2 + c2;  if (bb < 0 && a1 < rk && rk <= a1 + c1){ bb = lane*4+1; CC = a1; }
    int a0 = a1 + c1;  if (bb < 0 && a0 < rk && rk <= a0 + c0){ bb = lane*4+0; CC = a0; }
    unsigned long long mk = __ballot(bb >= 0);
    int src = (int)__ffsll(mk) - 1;
    bout = __shfl(bb, src); Cout = __shfl(CC, src);
  };

  // pass 1: high byte
  s_h[wave][lane*4+0] = 0; s_h[wave][lane*4+1] = 0;
  s_h[wave][lane*4+2] = 0; s_h[wave][lane*4+3] = 0;
  lds_fence();
#pragma unroll
  for (int e = 0; e < 16; e++) atomicAdd(&s_h[wave][kk[e] >> 8], 1);
  lds_fence();
  int b1, C1; findbin(64, b1, C1);

  // pass 2: low byte within bin b1
  s_h[wave][lane*4+0] = 0; s_h[wave][lane*4+1] = 0;
  s_h[wave][lane*4+2] = 0; s_h[wave][lane*4+3] = 0;
  lds_fence();
#pragma unroll
  for (int e = 0; e < 16; e++)
    if ((int)(kk[e] >> 8) == b1) atomicAdd(&s_h[wave][kk[e] & 255u], 1);
  lds_fence();
  int b2, C2; findbin(64 - C1, b2, C2);

  unsigned tkey = ((unsigned)b1 << 8) | (unsigned)b2;
  unsigned hthr = (tkey & 0x8000u) ? (tkey & 0x7FFFu) : (~tkey & 0xFFFFu);
  const float thr = bf2f((unsigned short)hthr);
  const float cl = thr - MARGIN, ch = thr + MARGIN;

  int n1 = 0;
#pragma unroll
  for (int e = 0; e < 16; e++) n1 += (vg[e] > ch) ? 1 : 0;
#pragma unroll
  for (int m = 32; m; m >>= 1) n1 += __shfl_xor(n1, m);
  const int s = 64 - n1;

  lds_fence();
#pragma unroll
  for (int e = 0; e < 16; e++){
    float vv = vg[e];
    if (vv >= cl && vv <= ch){
      int p = atomicAdd(&s_cnt[wave], 1);
      if (p < MAXC) s_idx[wave][p] = (e >> 3) * 512 + lane * 8 + (e & 7);
    }
  }
  lds_fence();
  int namb = s_cnt[wave]; if (namb > MAXC) namb = MAXC;

  // pipelined exact fp32 recompute of ambiguous dims
  const int o0 = lane * 8, o1 = lane * 8 + 4, o2 = 512 + lane * 8, o3 = 512 + lane * 8 + 4;
  float4 w0, w1, w2, w3;
  int dcur = 0;
  if (namb > 0){
    dcur = s_idx[wave][0];
    const float* wr0 = gW + (size_t)dcur * DIM;
    w0 = *(const float4*)(wr0 + o0); w1 = *(const float4*)(wr0 + o1);
    w2 = *(const float4*)(wr0 + o2); w3 = *(const float4*)(wr0 + o3);
  }
  for (int i = 0; i < namb; i++){
    float4 c0 = w0, c1 = w1, c2 = w2, c3 = w3;
    int dn = 0;
    if (i + 1 < namb){
      dn = s_idx[wave][i + 1];
      const float* wr2 = gW + (size_t)dn * DIM;
      w0 = *(const float4*)(wr2 + o0); w1 = *(const float4*)(wr2 + o1);
      w2 = *(const float4*)(wr2 + o2); w3 = *(const float4*)(wr2 + o3);
    }
    float p = 0.f;
    p = fmaf(vx[0], c0.x, p);  p = fmaf(vx[1], c0.y, p);
    p = fmaf(vx[2], c0.z, p);  p = fmaf(vx[3], c0.w, p);
    p = fmaf(vx[4], c1.x, p);  p = fmaf(vx[5], c1.y, p);
    p = fmaf(vx[6], c1.z, p);  p = fmaf(vx[7], c1.w, p);
    p = fmaf(vx[8], c2.x, p);  p = fmaf(vx[9], c2.y, p);
    p = fmaf(vx[10], c2.z, p); p = fmaf(vx[11], c2.w, p);
    p = fmaf(vx[12], c3.x, p); p = fmaf(vx[13], c3.y, p);
    p = fmaf(vx[14], c3.z, p); p = fmaf(vx[15], c3.w, p);
#pragma unroll
    for (int m = 32; m; m >>= 1) p += __shfl_xor(p, m);
    if (lane == 0) s_ex[wave][i] = p + gb[dcur];
    dcur = dn;
  }
  lds_fence();

  if (lane < namb){
    float e = s_ex[wave][lane]; int d = s_idx[wave][lane];
    int rank = 0;
    for (int j = 0; j < namb; j++){
      float ej = s_ex[wave][j]; int dj = s_idx[wave][j];
      if (ej > e || (ej == e && dj < d)) rank++;
    }
    s_res[wave][lane] = (rank < s && e > 0.f) ? 1 : 0;
  }
  lds_fence();

  // per-lane in-band membership/result masks (static vals indexing, rule #20)
  unsigned inb = 0, rsm = 0;
  for (int i = 0; i < namb; i++){
    int d = s_idx[wave][i];
    if (((d & 511) >> 3) == lane){
      int e = (d >> 9) * 8 + (d & 7);
      inb |= 1u << e;
      if (s_res[wave][i]) rsm |= 1u << e;
    }
  }

  float vals[16];
#pragma unroll
  for (int e = 0; e < 16; e++){
    float mv = (vm[e] > 0.f) ? vm[e] : 0.f;       // relu, -0 -> +0
    float v = (vg[e] > ch && vg[e] > 0.f) ? mv : 0.f;
    if ((inb >> e) & 1u) v = ((rsm >> e) & 1u) ? mv : 0.f;
    vals[e] = v;
  }

  unsigned pk[4];
#pragma unroll
  for (int q = 0; q < 4; q++){
    unsigned a = 0, b = 0;
    asm volatile("v_cvt_pk_fp8_f32 %0, %1, %2" : "+v"(a) : "v"(vals[4*q+0]), "v"(vals[4*q+1]));
    asm volatile("v_cvt_pk_fp8_f32 %0, %1, %2" : "+v"(b) : "v"(vals[4*q+2]), "v"(vals[4*q+3]));
    pk[q] = (a & 0xFFFFu) | (b << 16);
  }
  uint2 st0; st0.x = pk[0]; st0.y = pk[1];
  uint2 st1; st1.x = pk[2]; st1.y = pk[3];
  *(uint2*)(xg8 + rb + lane * 8) = st0;
  *(uint2*)(xg8 + rb + 512 + lane * 8) = st1;
}

// ------- epilogue: 4 rows/block, prev row + inverse-norms carried in registers -------
__global__ __launch_bounds__(256) void epilogue_k(
  const unsigned short* __restrict__ q_pre, const unsigned short* __restrict__ k_pre,
  const unsigned short* __restrict__ p_pre, float* __restrict__ out)
{
  const int r0 = blockIdx.x * 4;
  const int t = threadIdx.x;
  const int lane = t & 63, wave = t >> 6;
  __shared__ float red[16];

  const int rp = (r0 == 0) ? 0 : r0 - 1;
  float vqp[4], vkp[4], vpp[4];
  {
    ushort4 uq = *(const ushort4*)(q_pre + (size_t)rp * DIM + 4*t);
    ushort4 uk = *(const ushort4*)(k_pre + (size_t)rp * DIM + 4*t);
    ushort4 up = *(const ushort4*)(p_pre + (size_t)rp * DIM + 4*t);
    vqp[0]=bf2f(uq.x); vqp[1]=bf2f(uq.y); vqp[2]=bf2f(uq.z); vqp[3]=bf2f(uq.w);
    vkp[0]=bf2f(uk.x); vkp[1]=bf2f(uk.y); vkp[2]=bf2f(uk.z); vkp[3]=bf2f(uk.w);
    vpp[0]=bf2f(up.x); vpp[1]=bf2f(up.y); vpp[2]=bf2f(up.z); vpp[3]=bf2f(up.w);
  }
  float aq = 0.f, ak = 0.f;
#pragma unroll
  for (int j = 0; j < 4; j++){ aq = fmaf(vqp[j], vqp[j], aq); ak = fmaf(vkp[j], vkp[j], ak); }
#pragma unroll
  for (int m = 32; m; m >>= 1){ aq += __shfl_xor(aq, m); ak += __shfl_xor(ak, m); }
  if (lane == 0){ red[wave] = aq; red[4 + wave] = ak; }
  __syncthreads();
  float rqp = 1.f / fmaxf(sqrtf(red[0] + red[1] + red[2] + red[3]), 1e-12f);
  float rkp = 1.f / fmaxf(sqrtf(red[4] + red[5] + red[6] + red[7]), 1e-12f);
  __syncthreads();

  for (int rr = 0; rr < 4; rr++){
    const int r = r0 + rr;
    float vqc[4], vkc[4], vpc[4];
    {
      ushort4 uq = *(const ushort4*)(q_pre + (size_t)r * DIM + 4*t);
      ushort4 uk = *(const ushort4*)(k_pre + (size_t)r * DIM + 4*t);
      ushort4 up = *(const ushort4*)(p_pre + (size_t)r * DIM + 4*t);
      vqc[0]=bf2f(uq.x); vqc[1]=bf2f(uq.y); vqc[2]=bf2f(uq.z); vqc[3]=bf2f(uq.w);
      vkc[0]=bf2f(uk.x); vkc[1]=bf2f(uk.y); vkc[2]=bf2f(uk.z); vkc[3]=bf2f(uk.w);
      vpc[0]=bf2f(up.x); vpc[1]=bf2f(up.y); vpc[2]=bf2f(up.z); vpc[3]=bf2f(up.w);
    }
    const bool seg = (r & (SEQ - 1)) == 0;
    float aqc = 0.f, akc = 0.f;
#pragma unroll
    for (int j = 0; j < 4; j++){ aqc = fmaf(vqc[j], vqc[j], aqc); akc = fmaf(vkc[j], vkc[j], akc); }
    float dsum = 0.f;
    if (!seg){
#pragma unroll
      for (int j = 0; j < 2; j++){
        float ax = vpp[2*j], ay = vpp[2*j+1], bx = vpc[2*j], by = vpc[2*j+1];
        float ia = 1.f / fmaxf(sqrtf(ax * ax + ay * ay), 1e-12f);
        float ib = 1.f / fmaxf(sqrtf(bx * bx + by * by), 1e-12f);
        ax *= ia; ay *= ia; bx *= ib; by *= ib;
        float cross = ax * by - ay * bx;
        float dot = fminf(fmaxf(ax * bx + ay * by, -1.f), 1.f);
        dsum += fabsf(atan2f(cross, dot)) * 0.3183098861837907f;
      }
    }
#pragma unroll
    for (int m = 32; m; m >>= 1){
      aqc += __shfl_xor(aqc, m); akc += __shfl_xor(akc, m); dsum += __shfl_xor(dsum, m);
    }
    if (lane == 0){ red[wave] = aqc; red[4 + wave] = akc; red[8 + wave] = dsum; }
    __syncthreads();
    float rqc = 1.f / fmaxf(sqrtf(red[0] + red[1] + red[2] + red[3]), 1e-12f);
    float rkc = 1.f / fmaxf(sqrtf(red[4] + red[5] + red[6] + red[7]), 1e-12f);
    if (!seg){
      float tw = 0.f;
#pragma unroll
      for (int j = 0; j < 4; j++){
        float m = (vqc[j] * rqc) * (vkp[j] * rkp) - (vqp[j] * rqp) * (vkc[j] * rkc);
        tw = fmaf(m, m, tw);
      }
#pragma unroll
      for (int m = 32; m; m >>= 1) tw += __shfl_xor(tw, m);
      if (lane == 0) red[12 + wave] = tw;
      __syncthreads();
      if (t == 0){
        float dtot = red[8] + red[9] + red[10] + red[11];
        float twt = red[12] + red[13] + red[14] + red[15];
        out[r] = 0.5f * tanhf(sqrtf(twt)) + 0.5f * (dtot * (1.f / 512.f));
      }
    } else {
      if (t == 0) out[r] = 0.f;
    }
    __syncthreads();
#pragma unroll
    for (int j = 0; j < 4; j++){ vqp[j] = vqc[j]; vkp[j] = vkc[j]; vpp[j] = vpc[j]; }
    rqp = rqc; rkp = rkc;
  }
}

extern "C" void kernel_launch(void* const* d_in, const int* in_sizes, int n_in,
                              void* d_out, int out_size, void* d_ws, size_t ws_size,
                              hipStream_t stream)
{
  const float* x       = (const float*)d_in[0];
  const float* gate_W  = (const float*)d_in[1];
  const float* gate_b  = (const float*)d_in[2];
  const float* mag_W   = (const float*)d_in[3];
  const float* mag_b   = (const float*)d_in[4];
  const float* Wq      = (const float*)d_in[5];
  const float* Wk      = (const float*)d_in[6];
  const float* phase_W = (const float*)d_in[7];
  float* out = (float*)d_out;

  char* ws = (char*)d_ws;
  unsigned short* xbf = (unsigned short*)ws;                    // 32 MB @0 (reused as xg8)
  unsigned short* wbf = (unsigned short*)(ws + 33554432);       //  4 MB @32M: [gate;mag] bf16
  unsigned char*  wf8 = (unsigned char*)(ws + 37748736);        //  3 MB @36M: [q;k;p] fp8 x32
  unsigned short* gate_pre = (unsigned short*)(ws + 41943040);  // 32 MB @40M (reused as q_pre)
  unsigned short* mag_pre  = (unsigned short*)(ws + 75497472);  // 32 MB @72M (reused as k_pre)
  unsigned short* p_pre    = (unsigned short*)(ws + 109051904); // 32 MB @104M
  unsigned short* q_pre = gate_pre;
  unsigned short* k_pre = mag_pre;

  static bool attr_set = false;
  if (!attr_set){
    hipFuncSetAttribute((const void*)gemm_bt,
                        hipFuncAttributeMaxDynamicSharedMemorySize, 131072);
    hipFuncSetAttribute((const void*)gemm8,
                        hipFuncAttributeMaxDynamicSharedMemorySize, 65536);
    attr_set = true;
  }

  dim3 b256(256);
  cvt_all<<<dim3(1024, 21), b256, 0, stream>>>(x, gate_W, mag_W, Wq, Wk, phase_W,
                                               xbf, wbf, wf8);

  // gate+mag fused bf16 GEMM (N=2048): 256^2 tiles, balanced 8/4/8/4 phases
  gemm_bt<<<dim3(512), dim3(512), 131072, stream>>>(xbf, wbf, gate_b, mag_b,
                                                    gate_pre, mag_pre);

  unsigned char* xg8 = (unsigned char*)xbf;   // xbf no longer needed
  select_k<<<ROWS / 4, b256, 0, stream>>>(gate_pre, mag_pre, x, gate_W, gate_b, xg8);

  // q+k+phase MX-fp8 GEMM (N=3072): 128^2 tiles, dbuf LDS, 2 blocks/CU
  gemm8<<<dim3(3072), b256, 65536, stream>>>(xg8, wf8, q_pre, k_pre, p_pre);

  epilogue_k<<<ROWS / 4, b256, 0, stream>>>(q_pre, k_pre, p_pre, out);
}